// Round 5
// baseline (119.699 us; speedup 1.0000x reference)
//
#include <hip/hip_runtime.h>
#include <stdint.h>

#define E_DIM 512
#define L_IN  4096
#define L_OUT 4092   // L_IN - KW + 1
#define KW    5
#define B_DIM 8
#define L2P   4096   // padded row stride for y workspace
#define L_DS  2048   // downsampled output length
#define LP    4160   // padded length for transposed x

typedef __attribute__((ext_vector_type(8))) short short8;
typedef __attribute__((ext_vector_type(4))) float f32x4;

__device__ __forceinline__ unsigned short f2bf(float f) {
    uint32_t u = __float_as_uint(f);
    u += 0x7fffu + ((u >> 16) & 1);   // round-to-nearest-even
    return (unsigned short)(u >> 16);
}
__device__ __forceinline__ float bf2f(unsigned short h) {
    return __uint_as_float((uint32_t)h << 16);
}

// ---------------------------------------------------------------------------
// Converter 1: x [B][E][4096] f32 -> Xt [B][LP][E] bf16 (transposed; l-rows
// >= 4096 zeroed). f32 LDS tile [64][65] (2-way banks = free).
// ---------------------------------------------------------------------------
__global__ __launch_bounds__(256)
void xt_kernel(const float* __restrict__ x, unsigned short* __restrict__ Xt)
{
    const int b  = blockIdx.z;
    const int i0 = blockIdx.y * 64;
    const int l0 = blockIdx.x * 64;
    __shared__ float T[64][65];
    const int tid = threadIdx.x;

    const int ir = tid >> 4;          // 0..15
    const int cq = (tid & 15) * 4;    // 0..60
    #pragma unroll
    for (int jj = 0; jj < 4; ++jj) {
        int i = jj * 16 + ir;
        float4 v = make_float4(0.f, 0.f, 0.f, 0.f);
        if (l0 < L_IN)
            v = *reinterpret_cast<const float4*>(
                &x[((size_t)b * E_DIM + i0 + i) * L_IN + l0 + cq]);
        T[i][cq + 0] = v.x; T[i][cq + 1] = v.y;
        T[i][cq + 2] = v.z; T[i][cq + 3] = v.w;
    }
    __syncthreads();
    const int h  = tid & 31;          // i-pair
    const int rq = tid >> 5;          // 0..7
    #pragma unroll
    for (int j = 0; j < 8; ++j) {
        int lr = j * 8 + rq;
        ushort2 o;
        o.x = f2bf(T[2 * h][lr]);
        o.y = f2bf(T[2 * h + 1][lr]);
        *reinterpret_cast<ushort2*>(
            &Xt[((size_t)b * LP + l0 + lr) * E_DIM + i0 + 2 * h]) = o;
    }
}

// ---------------------------------------------------------------------------
// Converter 2: w [E][E][5] f32 -> Wt [5][E][E] bf16  (Wt[k][e][i] = w[e][i][k])
// ---------------------------------------------------------------------------
__global__ __launch_bounds__(256)
void wt_kernel(const float* __restrict__ w, unsigned short* __restrict__ Wt)
{
    int idx = blockIdx.x * 256 + threadIdx.x;   // e*512 + i
    if (idx >= E_DIM * E_DIM) return;
    #pragma unroll
    for (int k = 0; k < KW; ++k)
        Wt[(size_t)k * E_DIM * E_DIM + idx] = f2bf(w[(size_t)idx * KW + k]);
}

// ---------------------------------------------------------------------------
// Kernel 1: implicit-GEMM conv via MFMA (+ fused score partials).
// y[b,e,l] = sum_k sum_i Wt[k][e][i] * Xt[b][l+k][i] + bias[e]   (bf16 out)
// Block: 128(e) x 256(l), 4 waves (2x2), each wave 64e x 128l = 4x8 frags.
// Pipeline: X double-buffered (prefetch issued at start of compute(t),
// stays in flight across the raw barrier); W single-buffered (L2-resident,
// ~200cy drain). Raw s_barrier + explicit vmcnt(0) so the X prefetch is
// NOT drained at barrier #1 (T4 counted-vmcnt discipline).
// XOR swizzle f(row)=(row>>1)&3 on the 16B slot: conflict-free (verified 0).
// ---------------------------------------------------------------------------
#define XB_BYTES 17408                        // 272 rows x 64B
#define N_XCH    (XB_BYTES / 1024)            // 17 chunks
#define WOFF     (2 * XB_BYTES)               // 34816
#define WS_BYTES (5 * 128 * 64)               // 40960
#define N_WCH    (WS_BYTES / 1024)            // 40 chunks
#define LDS_BYTES (WOFF + WS_BYTES)           // 75776

__global__ __launch_bounds__(256, 2)
void conv_mfma(const unsigned short* __restrict__ Xt,
               const unsigned short* __restrict__ Wt,
               const float* __restrict__ bias,
               const float* __restrict__ sw,
               unsigned short* __restrict__ y,
               float* __restrict__ sp)
{
    __shared__ __align__(16) unsigned char lds[LDS_BYTES];
    const int l0 = blockIdx.x * 256;
    const int e0 = blockIdx.y * 128;
    const int b  = blockIdx.z;
    const int tid  = threadIdx.x;
    const int lane = tid & 63;
    const int wv   = tid >> 6;
    const int wr = wv >> 1, wc = wv & 1;      // e-half / l-half
    const int lr = lane & 15, lg = lane >> 4; // frag row / k-group
    const int ln4r = lane >> 2;               // row within 1KB chunk
    // stage-side source-column swizzle (lane-constant)
    const int xswz = ((lane & 3) ^ ((lane >> 3) & 3)) * 8;

    // fragment read addresses (swizzled), hoisted out of the K loop
    const int aBase = WOFF + (wr * 64 + lr) * 64
                    + ((lg ^ ((lr >> 1) & 3)) << 4);
    int bBase[KW];
    #pragma unroll
    for (int kt = 0; kt < KW; ++kt)
        bBase[kt] = (wc * 128 + lr + kt) * 64
                  + ((lg ^ (((lr + kt) >> 1) & 3)) << 4);

    const unsigned short* xt_base =
        Xt + ((size_t)b * LP + l0) * E_DIM + xswz;

    // ---- staging helpers ----
    auto stageX = [&](int buf, int i0) {
        for (int cch = wv; cch < N_XCH; cch += 4) {
            int row = cch * 16 + ln4r;                 // l_rel in [0,272)
            const unsigned short* gp = xt_base + (size_t)row * E_DIM + i0;
            __builtin_amdgcn_global_load_lds(
                (const __attribute__((address_space(1))) void*)gp,
                (__attribute__((address_space(3))) void*)(lds + buf * XB_BYTES + cch * 1024),
                16, 0, 0);
        }
    };
    auto stageW = [&](int i0) {
        for (int cch = wv; cch < N_WCH; cch += 4) {
            int rk = cch * 16 + ln4r;                  // k*128 + e_rel
            int k = rk >> 7, er = rk & 127;
            const unsigned short* gp =
                Wt + ((size_t)k * E_DIM + e0 + er) * E_DIM + i0 + xswz;
            __builtin_amdgcn_global_load_lds(
                (const __attribute__((address_space(1))) void*)gp,
                (__attribute__((address_space(3))) void*)(lds + WOFF + cch * 1024),
                16, 0, 0);
        }
    };

    f32x4 acc[4][8] = {};

    // prologue: stage X(0) + W(0), full drain
    stageX(0, 0);
    stageW(0);
    asm volatile("s_waitcnt vmcnt(0)" ::: "memory");
    __builtin_amdgcn_s_barrier();

    for (int ks = 0; ks < 16; ++ks) {
        const int par = ks & 1;
        // front-issue next X tile into the other buffer (in flight ~full step)
        if (ks < 15) stageX(par ^ 1, (ks + 1) * 32);

        #pragma unroll
        for (int kt = 0; kt < KW; ++kt) {
            short8 aF[4], bF[8];
            #pragma unroll
            for (int m = 0; m < 4; ++m)
                aF[m] = *reinterpret_cast<const short8*>(
                    &lds[aBase + (kt * 128 + m * 16) * 64]);
            #pragma unroll
            for (int n = 0; n < 8; ++n)
                bF[n] = *reinterpret_cast<const short8*>(
                    &lds[par * XB_BYTES + bBase[kt] + n * 1024]);
            #pragma unroll
            for (int m = 0; m < 4; ++m)
                #pragma unroll
                for (int n = 0; n < 8; ++n)
                    acc[m][n] = __builtin_amdgcn_mfma_f32_16x16x32_bf16(
                        aF[m], bF[n], acc[m][n], 0, 0, 0);
        }

        if (ks < 15) {
            // barrier 1: everyone done reading W(ks); X prefetch stays in flight
            __builtin_amdgcn_s_barrier();
            stageW((ks + 1) * 32);
            // drain own loads: W just issued (~L2 latency); X issued ~1 step ago
            asm volatile("s_waitcnt vmcnt(0)" ::: "memory");
            __builtin_amdgcn_s_barrier();
        }
    }

    // epilogue: C layout col(l)=lane&15, row(e)=(lane>>4)*4+q
    float spn[8] = {};
    #pragma unroll
    for (int m = 0; m < 4; ++m)
        #pragma unroll
        for (int q = 0; q < 4; ++q) {
            int e = e0 + wr * 64 + m * 16 + lg * 4 + q;
            float bv = bias[e];
            float wv_s = sw[e];
            unsigned short* yr =
                y + ((size_t)b * E_DIM + e) * L2P + l0 + wc * 128 + lr;
            #pragma unroll
            for (int n = 0; n < 8; ++n) {
                float v = acc[m][n][q] + bv;
                yr[n * 16] = f2bf(v);
                spn[n] = fmaf(v, wv_s, spn[n]);
            }
        }
    // reduce score partials over lg (lanes differing in bits 4,5)
    #pragma unroll
    for (int n = 0; n < 8; ++n) {
        float p = spn[n];
        p += __shfl_xor(p, 16);
        p += __shfl_xor(p, 32);
        if (lane < 16) {
            int l = l0 + wc * 128 + n * 16 + lane;
            sp[((size_t)b * L2P + l) * 8 + blockIdx.y * 2 + wr] = p;
        }
    }
}

// ---------------------------------------------------------------------------
// Kernel 2: fold score partials + per-position softmax weights over widths.
// ---------------------------------------------------------------------------
__global__ __launch_bounds__(256)
void weight_kernel(const float* __restrict__ sp, float* __restrict__ A)
{
    const int b  = blockIdx.y;
    const int l0 = blockIdx.x * 256;
    const int tid = threadIdx.x;
    __shared__ float sl[260];

    for (int idx = tid; idx < 260; idx += 256) {
        int l = l0 - 2 + idx;
        float v = 0.f;
        if (l >= 0 && l < L_OUT) {
            const float* p = &sp[((size_t)b * L2P + l) * 8];
            v = ((p[0] + p[1]) + (p[2] + p[3])) + ((p[4] + p[5]) + (p[6] + p[7]));
        }
        sl[idx] = v;
    }
    __syncthreads();

    const int l = l0 + tid;
    if (l >= L_OUT) return;
    #define SL(i) sl[(i) - (l0 - 2)]
    float sc0 = SL(l);
    int n2 = l & ~1;
    float sc1 = 0.5f * (SL(n2) + SL(n2 + 1));
    int n3 = (l / 3) * 3;
    float sc2 = (1.f / 3.f) * (SL(n3) + SL(n3 + 1) + SL(n3 + 2));
    int n4 = l & ~3;
    float sc3 = 0.25f * (SL(n4) + SL(n4 + 1) + SL(n4 + 2) + SL(n4 + 3));
    #undef SL

    float m  = fmaxf(fmaxf(sc0, sc1), fmaxf(sc2, sc3));
    float e0 = __expf(sc0 - m), e1 = __expf(sc1 - m);
    float e2 = __expf(sc2 - m), e3 = __expf(sc3 - m);
    float inv = 1.f / (e0 + e1 + e2 + e3);

    float4 av = make_float4(e0 * inv, e1 * inv, e2 * inv, e3 * inv);
    *reinterpret_cast<float4*>(&A[((size_t)b * L2P + l) * 4]) = av;
}

// ---------------------------------------------------------------------------
// Kernel 3: softmax-weighted combine + downsample-by-2 average.
// ---------------------------------------------------------------------------
typedef __attribute__((ext_vector_type(8))) unsigned short u16x8;

__global__ __launch_bounds__(256)
void combine_kernel(const unsigned short* __restrict__ y,
                    const float* __restrict__ A, float* __restrict__ out)
{
    const int e = blockIdx.x;
    const int b = blockIdx.y;
    const int tid = threadIdx.x;
    __shared__ float ys[L2P];

    const unsigned short* yrow = y + ((size_t)b * E_DIM + e) * L2P;
    #pragma unroll
    for (int j = 0; j < 2; ++j) {
        int base = (tid + j * 256) * 8;
        u16x8 v = *reinterpret_cast<const u16x8*>(&yrow[base]);
        #pragma unroll
        for (int t = 0; t < 8; ++t) ys[base + t] = bf2f(v[t]);
    }
    __syncthreads();

    const float* Ab = A + (size_t)b * L2P * 4;
    float* orow = out + ((size_t)b * E_DIM + e) * L_DS;
    #pragma unroll
    for (int j = 0; j < 8; ++j) {
        int m = tid + j * 256;
        float acc = 0.f;
        #pragma unroll
        for (int r = 0; r < 2; ++r) {
            int l = 2 * m + r;
            if (l < L_OUT) {
                const float4 a4 = *reinterpret_cast<const float4*>(&Ab[l * 4]);
                float t = a4.x * ys[l];
                int n2 = l & ~1;
                t += a4.y * 0.5f * (ys[n2] + ys[n2 + 1]);
                int n3 = (l / 3) * 3;
                t += a4.z * (1.f / 3.f) * (ys[n3] + ys[n3 + 1] + ys[n3 + 2]);
                int n4 = l & ~3;
                t += a4.w * 0.25f * (ys[n4] + ys[n4 + 1] + ys[n4 + 2] + ys[n4 + 3]);
                acc += t;
            }
        }
        orow[m] = 0.5f * acc;
    }
}

// ---------------------------------------------------------------------------
// Workspace layout:
//   Y  : B*E*L2P bf16            = 32 MB     conv output
//   SP : B*L2P*8 f32             =  1 MB     score partials (deterministic)
//   A  : B*L2P*4 f32             = 0.5 MB    softmax weights
//   Xt : B*LP*E bf16             = 32.5 MB   transposed x
//   Wt : 5*E*E bf16              =  2.6 MB
// total ~68.6 MB
// ---------------------------------------------------------------------------
extern "C" void kernel_launch(void* const* d_in, const int* in_sizes, int n_in,
                              void* d_out, int out_size, void* d_ws, size_t ws_size,
                              hipStream_t stream)
{
    const float* x  = (const float*)d_in[0];
    const float* w  = (const float*)d_in[1];
    const float* bb = (const float*)d_in[2];
    const float* sw = (const float*)d_in[3];
    float* out = (float*)d_out;

    unsigned short* Y = (unsigned short*)d_ws;
    float* SP = (float*)(Y + (size_t)B_DIM * E_DIM * L2P);
    float* A  = SP + (size_t)B_DIM * L2P * 8;
    unsigned short* Xt = (unsigned short*)(A + (size_t)B_DIM * L2P * 4);
    unsigned short* Wt = Xt + (size_t)B_DIM * LP * E_DIM;

    xt_kernel<<<dim3(LP / 64, E_DIM / 64, B_DIM), 256, 0, stream>>>(x, Xt);
    wt_kernel<<<dim3(E_DIM * E_DIM / 256), 256, 0, stream>>>(w, Wt);
    conv_mfma<<<dim3(L2P / 256, E_DIM / 128, B_DIM), 256, 0, stream>>>(Xt, Wt, bb, sw, Y, SP);
    weight_kernel<<<dim3(L2P / 256, B_DIM), 256, 0, stream>>>(SP, A);
    combine_kernel<<<dim3(E_DIM, B_DIM), 256, 0, stream>>>(Y, A, out);
}

// Round 6
// 116.110 us; speedup vs baseline: 1.0309x; 1.0309x over previous
//
#include <hip/hip_runtime.h>
#include <stdint.h>

#define E_DIM 512
#define L_IN  4096
#define L_OUT 4092   // L_IN - KW + 1
#define KW    5
#define B_DIM 8
#define L2P   4096   // padded row stride for y workspace
#define L_DS  2048   // downsampled output length
#define LP    4160   // padded length for transposed x

typedef __attribute__((ext_vector_type(8))) short short8;
typedef __attribute__((ext_vector_type(4))) float f32x4;

__device__ __forceinline__ unsigned short f2bf(float f) {
    uint32_t u = __float_as_uint(f);
    u += 0x7fffu + ((u >> 16) & 1);   // round-to-nearest-even
    return (unsigned short)(u >> 16);
}
__device__ __forceinline__ float bf2f(unsigned short h) {
    return __uint_as_float((uint32_t)h << 16);
}
__device__ __forceinline__ int mod3(int v) {   // v in [0,8]
    if (v >= 6) v -= 6;
    if (v >= 3) v -= 3;
    return v;
}

// ---------------------------------------------------------------------------
// Converter 1: x [B][E][4096] f32 -> Xt [B][LP][E] bf16 (transposed; l-rows
// >= 4096 zeroed). f32 LDS tile [64][65] (2-way banks = free).
// ---------------------------------------------------------------------------
__global__ __launch_bounds__(256)
void xt_kernel(const float* __restrict__ x, unsigned short* __restrict__ Xt)
{
    const int b  = blockIdx.z;
    const int i0 = blockIdx.y * 64;
    const int l0 = blockIdx.x * 64;
    __shared__ float T[64][65];
    const int tid = threadIdx.x;

    const int ir = tid >> 4;          // 0..15
    const int cq = (tid & 15) * 4;    // 0..60
    #pragma unroll
    for (int jj = 0; jj < 4; ++jj) {
        int i = jj * 16 + ir;
        float4 v = make_float4(0.f, 0.f, 0.f, 0.f);
        if (l0 < L_IN)
            v = *reinterpret_cast<const float4*>(
                &x[((size_t)b * E_DIM + i0 + i) * L_IN + l0 + cq]);
        T[i][cq + 0] = v.x; T[i][cq + 1] = v.y;
        T[i][cq + 2] = v.z; T[i][cq + 3] = v.w;
    }
    __syncthreads();
    const int h  = tid & 31;          // i-pair
    const int rq = tid >> 5;          // 0..7
    #pragma unroll
    for (int j = 0; j < 8; ++j) {
        int lr = j * 8 + rq;
        ushort2 o;
        o.x = f2bf(T[2 * h][lr]);
        o.y = f2bf(T[2 * h + 1][lr]);
        *reinterpret_cast<ushort2*>(
            &Xt[((size_t)b * LP + l0 + lr) * E_DIM + i0 + 2 * h]) = o;
    }
}

// ---------------------------------------------------------------------------
// Converter 2: w [E][E][5] f32 -> Wt [5][E][E] bf16  (Wt[k][e][i] = w[e][i][k])
// ---------------------------------------------------------------------------
__global__ __launch_bounds__(256)
void wt_kernel(const float* __restrict__ w, unsigned short* __restrict__ Wt)
{
    int idx = blockIdx.x * 256 + threadIdx.x;   // e*512 + i
    if (idx >= E_DIM * E_DIM) return;
    #pragma unroll
    for (int k = 0; k < KW; ++k)
        Wt[(size_t)k * E_DIM * E_DIM + idx] = f2bf(w[(size_t)idx * KW + k]);
}

// ---------------------------------------------------------------------------
// Kernel 1: implicit-GEMM conv via MFMA, 5-phase-per-K-step schedule.
// y[b,e,l] = sum_k sum_i Wt[k][e][i] * Xt[b][l+k][i] + bias[e]   (bf16 out)
// Block 128e x 256l, 4 waves 2x2, wave 64e x 128l (4x8 frags 16x16x32).
//
// Per phase g = ks*5+kt:  [12 ds_read (W slot g%3, X buf ks&1)]
//   [stage: X(ks+1) at kt==0; W slice g+2 into slot (g+2)%3]
//   [vmcnt(6 @kt0 / 2 else)] [barrier] [setprio(1) 32 MFMA setprio(0)] [barrier]
// Counted vmcnt (never 0 mid-loop): own-phase issues stay in flight; all
// deadline-due loads (issued >=1 phase ago) are forced. Slot overwrite is
// always >= 2 barriers after its last read.
// XOR swizzle f(row)=(row>>1)&3 on the 16B slot (bank-conflict-free, R4-verified).
// ---------------------------------------------------------------------------
#define XB_BYTES  17408                       // 272 rows x 64B per X buffer
#define WOFF      (2 * XB_BYTES)              // 34816
#define WSL_BYTES 8192                        // one W slice: 128e x 32i bf16
#define LDS_BYTES (WOFF + 3 * WSL_BYTES)      // 59392

__global__ __launch_bounds__(256, 2)
void conv_mfma(const unsigned short* __restrict__ Xt,
               const unsigned short* __restrict__ Wt,
               const float* __restrict__ bias,
               const float* __restrict__ sw,
               unsigned short* __restrict__ y,
               float* __restrict__ sp)
{
    __shared__ __align__(16) unsigned char lds[LDS_BYTES];
    const int l0 = blockIdx.x * 256;
    const int e0 = blockIdx.y * 128;
    const int b  = blockIdx.z;
    const int tid  = threadIdx.x;
    const int lane = tid & 63;
    const int wv   = tid >> 6;
    const int wr = wv >> 1, wc = wv & 1;      // e-half / l-half
    const int lr = lane & 15, lg = lane >> 4; // frag row / k-group
    const int ln4r = lane >> 2;               // row within 1KB chunk
    // stage-side source-column swizzle (lane-constant)
    const int xswz = ((lane & 3) ^ ((lane >> 3) & 3)) * 8;

    // fragment read offsets (swizzled), hoisted
    const int aOff = (wr * 64 + lr) * 64 + ((lg ^ ((lr >> 1) & 3)) << 4);
    int bBase[KW];
    #pragma unroll
    for (int kt = 0; kt < KW; ++kt)
        bBase[kt] = (wc * 128 + lr + kt) * 64
                  + ((lg ^ (((lr + kt) >> 1) & 3)) << 4);

    const unsigned short* xt_base =
        Xt + ((size_t)b * LP + l0) * E_DIM + xswz;

    // ---- staging helpers ----
    // X buffer: 17 chunks of 1KB; wave w handles chunks {w, w+4, w+8, w+12, 16(w0)}
    auto stageX = [&](int buf, int i0) {
        for (int cch = wv; cch < 17; cch += 4) {
            int row = cch * 16 + ln4r;                 // l_rel in [0,272)
            const unsigned short* gp = xt_base + (size_t)row * E_DIM + i0;
            __builtin_amdgcn_global_load_lds(
                (const __attribute__((address_space(1))) void*)gp,
                (__attribute__((address_space(3))) void*)(lds + buf * XB_BYTES + cch * 1024),
                16, 0, 0);
        }
    };
    // one W slice (tap, i0): 8 chunks of 1KB; 2 chunks per wave
    auto stageW = [&](int dstOff, int tap, int i0) {
        for (int cch = wv; cch < 8; cch += 4) {
            int er = cch * 16 + ln4r;                  // e_rel in [0,128)
            const unsigned short* gp =
                Wt + ((size_t)tap * E_DIM + e0 + er) * E_DIM + i0 + xswz;
            __builtin_amdgcn_global_load_lds(
                (const __attribute__((address_space(1))) void*)gp,
                (__attribute__((address_space(3))) void*)(lds + dstOff + cch * 1024),
                16, 0, 0);
        }
    };

    f32x4 acc[4][8] = {};

    // prologue: X(step0) + W slices g=0 (slot0), g=1 (slot1); full drain
    stageX(0, 0);
    stageW(WOFF + 0 * WSL_BYTES, 0, 0);
    stageW(WOFF + 1 * WSL_BYTES, 1, 0);
    asm volatile("s_waitcnt vmcnt(0)" ::: "memory");
    __builtin_amdgcn_s_barrier();

    int s0 = 0;                                   // (2*ks) % 3
    for (int ks = 0; ks < 16; ++ks) {
        const int par  = ks & 1;
        const int xoff = par * XB_BYTES;
        #pragma unroll
        for (int kt = 0; kt < KW; ++kt) {
            // 1) fragment reads (data staged >=2 phases ago, barrier-published)
            const int wsl = WOFF + mod3(s0 + kt) * WSL_BYTES;
            short8 aF[4], bF[8];
            #pragma unroll
            for (int m = 0; m < 4; ++m)
                aF[m] = *reinterpret_cast<const short8*>(
                    &lds[wsl + aOff + m * 1024]);
            #pragma unroll
            for (int n = 0; n < 8; ++n)
                bF[n] = *reinterpret_cast<const short8*>(
                    &lds[xoff + bBase[kt] + n * 1024]);

            // 2) stage issues
            if (kt == 0 && ks < 15) stageX(par ^ 1, (ks + 1) * 32);
            if (!(ks == 15 && kt >= 3)) {        // g+2 < 80
                const int dst = WOFF + mod3(s0 + kt + 2) * WSL_BYTES;
                if (kt <= 2) stageW(dst, kt + 2, ks * 32);
                else         stageW(dst, kt - 3, (ks + 1) * 32);
            }

            // 3) counted vmcnt: keep own-phase issues in flight, force older
            if (kt == 0) asm volatile("s_waitcnt vmcnt(6)" ::: "memory");
            else         asm volatile("s_waitcnt vmcnt(2)" ::: "memory");
            __builtin_amdgcn_s_barrier();

            // 4) MFMA cluster (compiler inserts lgkmcnt for aF/bF deps)
            __builtin_amdgcn_s_setprio(1);
            #pragma unroll
            for (int m = 0; m < 4; ++m)
                #pragma unroll
                for (int n = 0; n < 8; ++n)
                    acc[m][n] = __builtin_amdgcn_mfma_f32_16x16x32_bf16(
                        aF[m], bF[n], acc[m][n], 0, 0, 0);
            __builtin_amdgcn_s_setprio(0);
            __builtin_amdgcn_s_barrier();
        }
        s0 += 2; if (s0 >= 3) s0 -= 3;
    }

    // epilogue: C layout col(l)=lane&15, row(e)=(lane>>4)*4+q
    float spn[8] = {};
    #pragma unroll
    for (int m = 0; m < 4; ++m)
        #pragma unroll
        for (int q = 0; q < 4; ++q) {
            int e = e0 + wr * 64 + m * 16 + lg * 4 + q;
            float bv = bias[e];
            float wv_s = sw[e];
            unsigned short* yr =
                y + ((size_t)b * E_DIM + e) * L2P + l0 + wc * 128 + lr;
            #pragma unroll
            for (int n = 0; n < 8; ++n) {
                float v = acc[m][n][q] + bv;
                yr[n * 16] = f2bf(v);
                spn[n] = fmaf(v, wv_s, spn[n]);
            }
        }
    // reduce score partials over lg (lanes differing in bits 4,5)
    #pragma unroll
    for (int n = 0; n < 8; ++n) {
        float p = spn[n];
        p += __shfl_xor(p, 16);
        p += __shfl_xor(p, 32);
        if (lane < 16) {
            int l = l0 + wc * 128 + n * 16 + lane;
            sp[((size_t)b * L2P + l) * 8 + blockIdx.y * 2 + wr] = p;
        }
    }
}

// ---------------------------------------------------------------------------
// Kernel 2: fold score partials + per-position softmax weights over widths.
// ---------------------------------------------------------------------------
__global__ __launch_bounds__(256)
void weight_kernel(const float* __restrict__ sp, float* __restrict__ A)
{
    const int b  = blockIdx.y;
    const int l0 = blockIdx.x * 256;
    const int tid = threadIdx.x;
    __shared__ float sl[260];

    for (int idx = tid; idx < 260; idx += 256) {
        int l = l0 - 2 + idx;
        float v = 0.f;
        if (l >= 0 && l < L_OUT) {
            const float* p = &sp[((size_t)b * L2P + l) * 8];
            v = ((p[0] + p[1]) + (p[2] + p[3])) + ((p[4] + p[5]) + (p[6] + p[7]));
        }
        sl[idx] = v;
    }
    __syncthreads();

    const int l = l0 + tid;
    if (l >= L_OUT) return;
    #define SL(i) sl[(i) - (l0 - 2)]
    float sc0 = SL(l);
    int n2 = l & ~1;
    float sc1 = 0.5f * (SL(n2) + SL(n2 + 1));
    int n3 = (l / 3) * 3;
    float sc2 = (1.f / 3.f) * (SL(n3) + SL(n3 + 1) + SL(n3 + 2));
    int n4 = l & ~3;
    float sc3 = 0.25f * (SL(n4) + SL(n4 + 1) + SL(n4 + 2) + SL(n4 + 3));
    #undef SL

    float m  = fmaxf(fmaxf(sc0, sc1), fmaxf(sc2, sc3));
    float e0 = __expf(sc0 - m), e1 = __expf(sc1 - m);
    float e2 = __expf(sc2 - m), e3 = __expf(sc3 - m);
    float inv = 1.f / (e0 + e1 + e2 + e3);

    float4 av = make_float4(e0 * inv, e1 * inv, e2 * inv, e3 * inv);
    *reinterpret_cast<float4*>(&A[((size_t)b * L2P + l) * 4]) = av;
}

// ---------------------------------------------------------------------------
// Kernel 3: softmax-weighted combine + downsample-by-2 average.
// ---------------------------------------------------------------------------
typedef __attribute__((ext_vector_type(8))) unsigned short u16x8;

__global__ __launch_bounds__(256)
void combine_kernel(const unsigned short* __restrict__ y,
                    const float* __restrict__ A, float* __restrict__ out)
{
    const int e = blockIdx.x;
    const int b = blockIdx.y;
    const int tid = threadIdx.x;
    __shared__ float ys[L2P];

    const unsigned short* yrow = y + ((size_t)b * E_DIM + e) * L2P;
    #pragma unroll
    for (int j = 0; j < 2; ++j) {
        int base = (tid + j * 256) * 8;
        u16x8 v = *reinterpret_cast<const u16x8*>(&yrow[base]);
        #pragma unroll
        for (int t = 0; t < 8; ++t) ys[base + t] = bf2f(v[t]);
    }
    __syncthreads();

    const float* Ab = A + (size_t)b * L2P * 4;
    float* orow = out + ((size_t)b * E_DIM + e) * L_DS;
    #pragma unroll
    for (int j = 0; j < 8; ++j) {
        int m = tid + j * 256;
        float acc = 0.f;
        #pragma unroll
        for (int r = 0; r < 2; ++r) {
            int l = 2 * m + r;
            if (l < L_OUT) {
                const float4 a4 = *reinterpret_cast<const float4*>(&Ab[l * 4]);
                float t = a4.x * ys[l];
                int n2 = l & ~1;
                t += a4.y * 0.5f * (ys[n2] + ys[n2 + 1]);
                int n3 = (l / 3) * 3;
                t += a4.z * (1.f / 3.f) * (ys[n3] + ys[n3 + 1] + ys[n3 + 2]);
                int n4 = l & ~3;
                t += a4.w * 0.25f * (ys[n4] + ys[n4 + 1] + ys[n4 + 2] + ys[n4 + 3]);
                acc += t;
            }
        }
        orow[m] = 0.5f * acc;
    }
}

// ---------------------------------------------------------------------------
// Workspace layout:
//   Y  : B*E*L2P bf16            = 32 MB     conv output
//   SP : B*L2P*8 f32             =  1 MB     score partials (deterministic)
//   A  : B*L2P*4 f32             = 0.5 MB    softmax weights
//   Xt : B*LP*E bf16             = 32.5 MB   transposed x
//   Wt : 5*E*E bf16              =  2.6 MB
// total ~68.6 MB
// ---------------------------------------------------------------------------
extern "C" void kernel_launch(void* const* d_in, const int* in_sizes, int n_in,
                              void* d_out, int out_size, void* d_ws, size_t ws_size,
                              hipStream_t stream)
{
    const float* x  = (const float*)d_in[0];
    const float* w  = (const float*)d_in[1];
    const float* bb = (const float*)d_in[2];
    const float* sw = (const float*)d_in[3];
    float* out = (float*)d_out;

    unsigned short* Y = (unsigned short*)d_ws;
    float* SP = (float*)(Y + (size_t)B_DIM * E_DIM * L2P);
    float* A  = SP + (size_t)B_DIM * L2P * 8;
    unsigned short* Xt = (unsigned short*)(A + (size_t)B_DIM * L2P * 4);
    unsigned short* Wt = Xt + (size_t)B_DIM * LP * E_DIM;

    xt_kernel<<<dim3(LP / 64, E_DIM / 64, B_DIM), 256, 0, stream>>>(x, Xt);
    wt_kernel<<<dim3(E_DIM * E_DIM / 256), 256, 0, stream>>>(w, Wt);
    conv_mfma<<<dim3(L2P / 256, E_DIM / 128, B_DIM), 256, 0, stream>>>(Xt, Wt, bb, sw, Y, SP);
    weight_kernel<<<dim3(L2P / 256, B_DIM), 256, 0, stream>>>(SP, A);
    combine_kernel<<<dim3(E_DIM, B_DIM), 256, 0, stream>>>(Y, A, out);
}